// Round 1
// baseline (520.489 us; speedup 1.0000x reference)
//
#include <hip/hip_runtime.h>
#include <math.h>

#define Bdim 256
#define Ndim 4096
#define Mdim 64
#define EPSF 1e-16f

// ---------------------------------------------------------------------------
// Pass A: q[b,n] = dot(mem+eps, k+eps) / max(||mem+eps||, 1e-8)
// (k-norm factored out; folded into beta in pass B)
// Block = 256 threads handles 64 rows of one batch. Grid = B * (N/64).
// Thread layout: t&15 = float4 column index (16 x float4 = 64 floats/row),
//                t>>4 = row within 16-row group; 4 iterations.
// ---------------------------------------------------------------------------
__global__ __launch_bounds__(256) void pass_a_kernel(
    const float* __restrict__ mem, const float* __restrict__ k,
    float* __restrict__ q)
{
    const int blocks_per_b = Ndim / 64;
    const int b = blockIdx.x / blocks_per_b;
    const int rowbase = (blockIdx.x % blocks_per_b) * 64;
    const int t = threadIdx.x;
    const int m4 = t & 15;
    const int rsub = t >> 4;

    float4 ke = reinterpret_cast<const float4*>(k + b * Mdim)[m4];
    ke.x += EPSF; ke.y += EPSF; ke.z += EPSF; ke.w += EPSF;

    const float4* memb = reinterpret_cast<const float4*>(mem + (size_t)b * Ndim * Mdim);

    #pragma unroll
    for (int it = 0; it < 4; ++it) {
        const int row = rowbase + it * 16 + rsub;
        float4 mv = memb[row * 16 + m4];
        mv.x += EPSF; mv.y += EPSF; mv.z += EPSF; mv.w += EPSF;
        float d  = mv.x * ke.x + mv.y * ke.y + mv.z * ke.z + mv.w * ke.w;
        float nr = mv.x * mv.x + mv.y * mv.y + mv.z * mv.z + mv.w * mv.w;
        // reduce across the 16 lanes that share this row (xor masks stay in-group)
        #pragma unroll
        for (int mask = 1; mask < 16; mask <<= 1) {
            d  += __shfl_xor(d, mask);
            nr += __shfl_xor(nr, mask);
        }
        if (m4 == 0) {
            const float mn = fmaxf(sqrtf(nr), 1e-8f);
            q[b * Ndim + row] = d / mn;
        }
    }
}

// ---------------------------------------------------------------------------
// Pass B: one block per batch. softmax(beta*cos) -> gate -> circular conv
// -> pow(gamma) -> normalize -> w  (written straight into d_out's w region).
// ---------------------------------------------------------------------------
__device__ __forceinline__ float block_reduce_sum(float v, float* red, int t)
{
    const int lane = t & 63, wave = t >> 6;
    #pragma unroll
    for (int mask = 32; mask; mask >>= 1) v += __shfl_xor(v, mask);
    __syncthreads();                 // protect red[] reuse
    if (lane == 0) red[wave] = v;
    __syncthreads();
    return red[0] + red[1] + red[2] + red[3];
}

__device__ __forceinline__ float block_reduce_max(float v, float* red, int t)
{
    const int lane = t & 63, wave = t >> 6;
    #pragma unroll
    for (int mask = 32; mask; mask >>= 1) v = fmaxf(v, __shfl_xor(v, mask));
    __syncthreads();
    if (lane == 0) red[wave] = v;
    __syncthreads();
    return fmaxf(fmaxf(red[0], red[1]), fmaxf(red[2], red[3]));
}

__global__ __launch_bounds__(256) void pass_b_kernel(
    const float* __restrict__ q, const float* __restrict__ k,
    const float* __restrict__ beta, const float* __restrict__ g,
    const float* __restrict__ s, const float* __restrict__ gamma,
    const float* __restrict__ w_prev, float* __restrict__ w_out)
{
    __shared__ float wg_lds[Ndim];
    __shared__ float red[4];
    __shared__ float sh_kn;

    const int b = blockIdx.x;
    const int t = threadIdx.x;
    const int lane = t & 63, wave = t >> 6;

    // k_n = max(sqrt(sum((k+eps)^2)), 1e-8): wave 0, one element/lane (M==64)
    if (wave == 0) {
        float v = k[b * Mdim + lane] + EPSF;
        float sq = v * v;
        #pragma unroll
        for (int mask = 32; mask; mask >>= 1) sq += __shfl_xor(sq, mask);
        if (lane == 0) sh_kn = fmaxf(sqrtf(sq), 1e-8f);
    }
    __syncthreads();

    const float beta_eff = beta[b] / sh_kn;   // beta*cos = beta_eff * q
    const float gb = g[b];
    const float s0 = s[b * 3 + 0], s1 = s[b * 3 + 1], s2 = s[b * 3 + 2];
    const float gam = gamma[b];

    const float4* q4  = reinterpret_cast<const float4*>(q + (size_t)b * Ndim);
    const float4* wp4 = reinterpret_cast<const float4*>(w_prev + (size_t)b * Ndim);

    // z = beta_eff * q ; track max
    float4 zv[4];
    float zmax = -1e30f;
    #pragma unroll
    for (int i = 0; i < 4; ++i) {
        float4 v = q4[t + i * 256];
        v.x *= beta_eff; v.y *= beta_eff; v.z *= beta_eff; v.w *= beta_eff;
        zv[i] = v;
        zmax = fmaxf(zmax, fmaxf(fmaxf(v.x, v.y), fmaxf(v.z, v.w)));
    }
    zmax = block_reduce_max(zmax, red, t);

    // exp + sum
    float esum = 0.f;
    #pragma unroll
    for (int i = 0; i < 4; ++i) {
        zv[i].x = expf(zv[i].x - zmax); zv[i].y = expf(zv[i].y - zmax);
        zv[i].z = expf(zv[i].z - zmax); zv[i].w = expf(zv[i].w - zmax);
        esum += zv[i].x + zv[i].y + zv[i].z + zv[i].w;
    }
    esum = block_reduce_sum(esum, red, t);
    const float inv_esum = 1.0f / esum;

    // wg = g*wc + (1-g)*w_prev ; stash full row in LDS for the circular conv
    float4 wgv[4];
    #pragma unroll
    for (int i = 0; i < 4; ++i) {
        float4 wp = wp4[t + i * 256];
        float4 w;
        w.x = gb * (zv[i].x * inv_esum) + (1.f - gb) * wp.x;
        w.y = gb * (zv[i].y * inv_esum) + (1.f - gb) * wp.y;
        w.z = gb * (zv[i].z * inv_esum) + (1.f - gb) * wp.z;
        w.w = gb * (zv[i].w * inv_esum) + (1.f - gb) * wp.w;
        wgv[i] = w;
        reinterpret_cast<float4*>(wg_lds)[t + i * 256] = w;
    }
    __syncthreads();

    // circular 3-tap conv + sharpen
    float4 wpv[4];
    float psum = 0.f;
    #pragma unroll
    for (int i = 0; i < 4; ++i) {
        const int n0 = 4 * (t + i * 256);
        const float left  = wg_lds[(n0 + Ndim - 1) & (Ndim - 1)];
        const float right = wg_lds[(n0 + 4) & (Ndim - 1)];
        const float4 w = wgv[i];
        float4 h;
        h.x = s0 * left + s1 * w.x + s2 * w.y;
        h.y = s0 * w.x  + s1 * w.y + s2 * w.z;
        h.z = s0 * w.y  + s1 * w.z + s2 * w.w;
        h.w = s0 * w.z  + s1 * w.w + s2 * right;
        h.x = powf(h.x, gam); h.y = powf(h.y, gam);
        h.z = powf(h.z, gam); h.w = powf(h.w, gam);
        wpv[i] = h;
        psum += h.x + h.y + h.z + h.w;
    }
    psum = block_reduce_sum(psum, red, t);
    const float inv_psum = 1.0f / (psum + EPSF);

    float4* wout4 = reinterpret_cast<float4*>(w_out + (size_t)b * Ndim);
    #pragma unroll
    for (int i = 0; i < 4; ++i) {
        float4 h = wpv[i];
        h.x *= inv_psum; h.y *= inv_psum; h.z *= inv_psum; h.w *= inv_psum;
        wout4[t + i * 256] = h;
    }
}

// ---------------------------------------------------------------------------
// Pass C: stream memory once: rd += w[n]*mem[n,:], new_mem = mem*(1-w*e)+w*a.
// Grid = B * NCHUNK blocks; each block handles N/NCHUNK rows.
// ---------------------------------------------------------------------------
#define NCHUNK_C 8

__global__ __launch_bounds__(256) void pass_c_kernel(
    const float* __restrict__ mem, const float* __restrict__ e,
    const float* __restrict__ a, const float* __restrict__ w,
    float* __restrict__ rd, float* __restrict__ new_mem)
{
    const int b = blockIdx.x / NCHUNK_C;
    const int chunk = blockIdx.x % NCHUNK_C;
    const int rowbase = chunk * (Ndim / NCHUNK_C);
    const int t = threadIdx.x;
    const int m4 = t & 15;
    const int rsub = t >> 4;
    const int lane = t & 63, wave = t >> 6;

    float4 ev = reinterpret_cast<const float4*>(e + b * Mdim)[m4];
    float4 av = reinterpret_cast<const float4*>(a + b * Mdim)[m4];

    const float4* memb = reinterpret_cast<const float4*>(mem + (size_t)b * Ndim * Mdim);
    float4* nmb = reinterpret_cast<float4*>(new_mem + (size_t)b * Ndim * Mdim);
    const float* wb = w + (size_t)b * Ndim;

    float4 acc = {0.f, 0.f, 0.f, 0.f};

    #pragma unroll 4
    for (int it = 0; it < (Ndim / NCHUNK_C) / 16; ++it) {   // 32 iterations
        const int row = rowbase + it * 16 + rsub;
        const float wr = wb[row];
        float4 mv = memb[row * 16 + m4];
        acc.x += wr * mv.x; acc.y += wr * mv.y;
        acc.z += wr * mv.z; acc.w += wr * mv.w;
        float4 nm;
        nm.x = mv.x * (1.f - wr * ev.x) + wr * av.x;
        nm.y = mv.y * (1.f - wr * ev.y) + wr * av.y;
        nm.z = mv.z * (1.f - wr * ev.z) + wr * av.z;
        nm.w = mv.w * (1.f - wr * ev.w) + wr * av.w;
        nmb[row * 16 + m4] = nm;
    }

    // reduce acc across the 4 row-groups within each wave (lanes l, l^16, l^32, l^48)
    #pragma unroll
    for (int mask = 16; mask <= 32; mask <<= 1) {
        acc.x += __shfl_xor(acc.x, mask);
        acc.y += __shfl_xor(acc.y, mask);
        acc.z += __shfl_xor(acc.z, mask);
        acc.w += __shfl_xor(acc.w, mask);
    }

    __shared__ float4 redc[4][16];
    if (lane < 16) redc[wave][lane] = acc;
    __syncthreads();

    if (t < 16) {
        float4 tot = redc[0][t];
        #pragma unroll
        for (int wv = 1; wv < 4; ++wv) {
            tot.x += redc[wv][t].x; tot.y += redc[wv][t].y;
            tot.z += redc[wv][t].z; tot.w += redc[wv][t].w;
        }
        float* dst = rd + b * Mdim + t * 4;
        atomicAdd(dst + 0, tot.x);
        atomicAdd(dst + 1, tot.y);
        atomicAdd(dst + 2, tot.z);
        atomicAdd(dst + 3, tot.w);
    }
}

// ---------------------------------------------------------------------------
extern "C" void kernel_launch(void* const* d_in, const int* in_sizes, int n_in,
                              void* d_out, int out_size, void* d_ws, size_t ws_size,
                              hipStream_t stream)
{
    const float* mem    = (const float*)d_in[0];
    const float* k      = (const float*)d_in[1];
    const float* beta   = (const float*)d_in[2];
    const float* g      = (const float*)d_in[3];
    const float* s      = (const float*)d_in[4];
    const float* gamma  = (const float*)d_in[5];
    const float* w_prev = (const float*)d_in[6];
    const float* e      = (const float*)d_in[7];
    const float* a      = (const float*)d_in[8];

    float* out     = (float*)d_out;
    float* rd      = out;                                   // [B, M]
    float* new_mem = out + Bdim * Mdim;                     // [B, N, M]
    float* w_out   = out + Bdim * Mdim + (size_t)Bdim * Ndim * Mdim; // [B, N]

    float* q = (float*)d_ws;                                // [B, N] scratch

    hipMemsetAsync(rd, 0, Bdim * Mdim * sizeof(float), stream);

    pass_a_kernel<<<Bdim * (Ndim / 64), 256, 0, stream>>>(mem, k, q);
    pass_b_kernel<<<Bdim, 256, 0, stream>>>(q, k, beta, g, s, gamma, w_prev, w_out);
    pass_c_kernel<<<Bdim * NCHUNK_C, 256, 0, stream>>>(mem, e, a, w_out, rd, new_mem);
}

// Round 3
// 505.444 us; speedup vs baseline: 1.0298x; 1.0298x over previous
//
#include <hip/hip_runtime.h>
#include <math.h>

#define Bdim 256
#define Ndim 4096
#define Mdim 64
#define EPSF 1e-16f

typedef float vf4 __attribute__((ext_vector_type(4)));

// ---------------------------------------------------------------------------
// Pass A: q[b,n] = dot(mem+eps, k+eps) / max(||mem+eps||, 1e-8)
// (k-norm factored out; folded into beta in pass B)
// Block = 256 threads handles 64 rows of one batch. Grid = B * (N/64).
// Reads `memory` sequentially ascending -> L3 (256 MiB) ends up holding the
// TAIL of memory; pass C exploits this by traversing in reverse.
// ---------------------------------------------------------------------------
__global__ __launch_bounds__(256) void pass_a_kernel(
    const float* __restrict__ mem, const float* __restrict__ k,
    float* __restrict__ q)
{
    const int blocks_per_b = Ndim / 64;
    const int b = blockIdx.x / blocks_per_b;
    const int rowbase = (blockIdx.x % blocks_per_b) * 64;
    const int t = threadIdx.x;
    const int m4 = t & 15;
    const int rsub = t >> 4;

    float4 ke = reinterpret_cast<const float4*>(k + b * Mdim)[m4];
    ke.x += EPSF; ke.y += EPSF; ke.z += EPSF; ke.w += EPSF;

    const float4* memb = reinterpret_cast<const float4*>(mem + (size_t)b * Ndim * Mdim);

    #pragma unroll
    for (int it = 0; it < 4; ++it) {
        const int row = rowbase + it * 16 + rsub;
        float4 mv = memb[row * 16 + m4];
        mv.x += EPSF; mv.y += EPSF; mv.z += EPSF; mv.w += EPSF;
        float d  = mv.x * ke.x + mv.y * ke.y + mv.z * ke.z + mv.w * ke.w;
        float nr = mv.x * mv.x + mv.y * mv.y + mv.z * mv.z + mv.w * mv.w;
        // reduce across the 16 lanes that share this row (xor masks stay in-group)
        #pragma unroll
        for (int mask = 1; mask < 16; mask <<= 1) {
            d  += __shfl_xor(d, mask);
            nr += __shfl_xor(nr, mask);
        }
        if (m4 == 0) {
            const float mn = fmaxf(sqrtf(nr), 1e-8f);
            q[b * Ndim + row] = d / mn;
        }
    }
}

// ---------------------------------------------------------------------------
// Pass B: one block per batch. softmax(beta*cos) -> gate -> circular conv
// -> pow(gamma) -> normalize -> w. Also zeroes rd[b,:] for pass C's atomics
// (stream order guarantees completion before pass C starts).
// ---------------------------------------------------------------------------
__device__ __forceinline__ float block_reduce_sum(float v, float* red, int t)
{
    const int lane = t & 63, wave = t >> 6;
    #pragma unroll
    for (int mask = 32; mask; mask >>= 1) v += __shfl_xor(v, mask);
    __syncthreads();                 // protect red[] reuse
    if (lane == 0) red[wave] = v;
    __syncthreads();
    return red[0] + red[1] + red[2] + red[3];
}

__device__ __forceinline__ float block_reduce_max(float v, float* red, int t)
{
    const int lane = t & 63, wave = t >> 6;
    #pragma unroll
    for (int mask = 32; mask; mask >>= 1) v = fmaxf(v, __shfl_xor(v, mask));
    __syncthreads();
    if (lane == 0) red[wave] = v;
    __syncthreads();
    return fmaxf(fmaxf(red[0], red[1]), fmaxf(red[2], red[3]));
}

__global__ __launch_bounds__(256) void pass_b_kernel(
    const float* __restrict__ q, const float* __restrict__ k,
    const float* __restrict__ beta, const float* __restrict__ g,
    const float* __restrict__ s, const float* __restrict__ gamma,
    const float* __restrict__ w_prev, float* __restrict__ w_out,
    float* __restrict__ rd)
{
    __shared__ float wg_lds[Ndim];
    __shared__ float red[4];
    __shared__ float sh_kn;

    const int b = blockIdx.x;
    const int t = threadIdx.x;
    const int lane = t & 63, wave = t >> 6;

    // zero rd[b,:] for pass C's atomics (wave 1 to overlap with wave 0's k-norm)
    if (wave == 1) rd[b * Mdim + lane] = 0.0f;

    // k_n = max(sqrt(sum((k+eps)^2)), 1e-8): wave 0, one element/lane (M==64)
    if (wave == 0) {
        float v = k[b * Mdim + lane] + EPSF;
        float sq = v * v;
        #pragma unroll
        for (int mask = 32; mask; mask >>= 1) sq += __shfl_xor(sq, mask);
        if (lane == 0) sh_kn = fmaxf(sqrtf(sq), 1e-8f);
    }
    __syncthreads();

    const float beta_eff = beta[b] / sh_kn;   // beta*cos = beta_eff * q
    const float gb = g[b];
    const float s0 = s[b * 3 + 0], s1 = s[b * 3 + 1], s2 = s[b * 3 + 2];
    const float gam = gamma[b];

    const float4* q4  = reinterpret_cast<const float4*>(q + (size_t)b * Ndim);
    const float4* wp4 = reinterpret_cast<const float4*>(w_prev + (size_t)b * Ndim);

    // z = beta_eff * q ; track max
    float4 zv[4];
    float zmax = -1e30f;
    #pragma unroll
    for (int i = 0; i < 4; ++i) {
        float4 v = q4[t + i * 256];
        v.x *= beta_eff; v.y *= beta_eff; v.z *= beta_eff; v.w *= beta_eff;
        zv[i] = v;
        zmax = fmaxf(zmax, fmaxf(fmaxf(v.x, v.y), fmaxf(v.z, v.w)));
    }
    zmax = block_reduce_max(zmax, red, t);

    // exp + sum
    float esum = 0.f;
    #pragma unroll
    for (int i = 0; i < 4; ++i) {
        zv[i].x = expf(zv[i].x - zmax); zv[i].y = expf(zv[i].y - zmax);
        zv[i].z = expf(zv[i].z - zmax); zv[i].w = expf(zv[i].w - zmax);
        esum += zv[i].x + zv[i].y + zv[i].z + zv[i].w;
    }
    esum = block_reduce_sum(esum, red, t);
    const float inv_esum = 1.0f / esum;

    // wg = g*wc + (1-g)*w_prev ; stash full row in LDS for the circular conv
    float4 wgv[4];
    #pragma unroll
    for (int i = 0; i < 4; ++i) {
        float4 wp = wp4[t + i * 256];
        float4 w;
        w.x = gb * (zv[i].x * inv_esum) + (1.f - gb) * wp.x;
        w.y = gb * (zv[i].y * inv_esum) + (1.f - gb) * wp.y;
        w.z = gb * (zv[i].z * inv_esum) + (1.f - gb) * wp.z;
        w.w = gb * (zv[i].w * inv_esum) + (1.f - gb) * wp.w;
        wgv[i] = w;
        reinterpret_cast<float4*>(wg_lds)[t + i * 256] = w;
    }
    __syncthreads();

    // circular 3-tap conv + sharpen
    float4 wpv[4];
    float psum = 0.f;
    #pragma unroll
    for (int i = 0; i < 4; ++i) {
        const int n0 = 4 * (t + i * 256);
        const float left  = wg_lds[(n0 + Ndim - 1) & (Ndim - 1)];
        const float right = wg_lds[(n0 + 4) & (Ndim - 1)];
        const float4 w = wgv[i];
        float4 h;
        h.x = s0 * left + s1 * w.x + s2 * w.y;
        h.y = s0 * w.x  + s1 * w.y + s2 * w.z;
        h.z = s0 * w.y  + s1 * w.z + s2 * w.w;
        h.w = s0 * w.z  + s1 * w.w + s2 * right;
        h.x = powf(h.x, gam); h.y = powf(h.y, gam);
        h.z = powf(h.z, gam); h.w = powf(h.w, gam);
        wpv[i] = h;
        psum += h.x + h.y + h.z + h.w;
    }
    psum = block_reduce_sum(psum, red, t);
    const float inv_psum = 1.0f / (psum + EPSF);

    float4* wout4 = reinterpret_cast<float4*>(w_out + (size_t)b * Ndim);
    #pragma unroll
    for (int i = 0; i < 4; ++i) {
        float4 h = wpv[i];
        h.x *= inv_psum; h.y *= inv_psum; h.z *= inv_psum; h.w *= inv_psum;
        wout4[t + i * 256] = h;
    }
}

// ---------------------------------------------------------------------------
// Pass C: stream memory once: rd += w[n]*mem[n,:], new_mem = mem*(1-w*e)+w*a.
// Traverses `memory` in REVERSE (block mapping + inner loop descending) so the
// most-recently-L3-cached lines from pass A are read first (stack-order
// traversal of an LRU cache). new_mem stores are non-temporal so the 256 MiB
// of write data does not evict the memory lines we still want to read.
// ---------------------------------------------------------------------------
#define NCHUNK_C 8

__global__ __launch_bounds__(256) void pass_c_kernel(
    const float* __restrict__ mem, const float* __restrict__ e,
    const float* __restrict__ a, const float* __restrict__ w,
    float* __restrict__ rd, float* __restrict__ new_mem)
{
    // reversed block mapping: highest addresses processed by lowest blockIdx
    const int idx = (Bdim * NCHUNK_C - 1) - (int)blockIdx.x;
    const int b = idx / NCHUNK_C;
    const int chunk = idx % NCHUNK_C;
    const int rowbase = chunk * (Ndim / NCHUNK_C);
    const int t = threadIdx.x;
    const int m4 = t & 15;
    const int rsub = t >> 4;
    const int lane = t & 63, wave = t >> 6;

    float4 ev4 = reinterpret_cast<const float4*>(e + b * Mdim)[m4];
    float4 av4 = reinterpret_cast<const float4*>(a + b * Mdim)[m4];
    vf4 ev = {ev4.x, ev4.y, ev4.z, ev4.w};
    vf4 av = {av4.x, av4.y, av4.z, av4.w};

    const vf4* memb = reinterpret_cast<const vf4*>(mem + (size_t)b * Ndim * Mdim);
    vf4* nmb = reinterpret_cast<vf4*>(new_mem + (size_t)b * Ndim * Mdim);
    const float* wb = w + (size_t)b * Ndim;

    vf4 acc = {0.f, 0.f, 0.f, 0.f};

    #pragma unroll 4
    for (int it2 = 0; it2 < (Ndim / NCHUNK_C) / 16; ++it2) {   // 32 iterations
        const int it = ((Ndim / NCHUNK_C) / 16 - 1) - it2;     // descending
        const int row = rowbase + it * 16 + rsub;
        const float wr = wb[row];
        vf4 mv = memb[row * 16 + m4];
        acc += wr * mv;
        vf4 nm = mv * (1.f - wr * ev) + wr * av;
        __builtin_nontemporal_store(nm, &nmb[row * 16 + m4]);
    }

    // reduce acc across the 4 row-groups within each wave (lanes l, l^16, l^32, l^48)
    #pragma unroll
    for (int mask = 16; mask <= 32; mask <<= 1) {
        acc.x += __shfl_xor(acc.x, mask);
        acc.y += __shfl_xor(acc.y, mask);
        acc.z += __shfl_xor(acc.z, mask);
        acc.w += __shfl_xor(acc.w, mask);
    }

    __shared__ vf4 redc[4][16];
    if (lane < 16) redc[wave][lane] = acc;
    __syncthreads();

    if (t < 16) {
        vf4 tot = redc[0][t];
        #pragma unroll
        for (int wv = 1; wv < 4; ++wv) tot += redc[wv][t];
        float* dst = rd + b * Mdim + t * 4;
        atomicAdd(dst + 0, tot.x);
        atomicAdd(dst + 1, tot.y);
        atomicAdd(dst + 2, tot.z);
        atomicAdd(dst + 3, tot.w);
    }
}

// ---------------------------------------------------------------------------
extern "C" void kernel_launch(void* const* d_in, const int* in_sizes, int n_in,
                              void* d_out, int out_size, void* d_ws, size_t ws_size,
                              hipStream_t stream)
{
    const float* mem    = (const float*)d_in[0];
    const float* k      = (const float*)d_in[1];
    const float* beta   = (const float*)d_in[2];
    const float* g      = (const float*)d_in[3];
    const float* s      = (const float*)d_in[4];
    const float* gamma  = (const float*)d_in[5];
    const float* w_prev = (const float*)d_in[6];
    const float* e      = (const float*)d_in[7];
    const float* a      = (const float*)d_in[8];

    float* out     = (float*)d_out;
    float* rd      = out;                                   // [B, M]
    float* new_mem = out + Bdim * Mdim;                     // [B, N, M]
    float* w_out   = out + Bdim * Mdim + (size_t)Bdim * Ndim * Mdim; // [B, N]

    float* q = (float*)d_ws;                                // [B, N] scratch

    pass_a_kernel<<<Bdim * (Ndim / 64), 256, 0, stream>>>(mem, k, q);
    pass_b_kernel<<<Bdim, 256, 0, stream>>>(q, k, beta, g, s, gamma, w_prev, w_out, rd);
    pass_c_kernel<<<Bdim * NCHUNK_C, 256, 0, stream>>>(mem, e, a, w_out, rd, new_mem);
}